// Round 7
// baseline (41267.889 us; speedup 1.0000x reference)
//
#include <hip/hip_runtime.h>
#include <math.h>

// EncoderDecoder LSTM seq2seq, f32 throughout.
// v5: LDS-volume reduction (the validated bottleneck: v2 ~= 18ms model vs 16.8
// measured, pure LDS-read-bound). Cell 4bx4r tile (2 B/MAC vs v2's 6), logits
// 2bx8v (2.5 vs 5). K-split index lives in the LOW tid bits so every wave's
// reads spread over all 8 bank-quads (derived lane->bank maps; unified XOR
// swizzle on store+read). __launch_bounds__(512,4) caps VGPR at 128 (v4's
// occupancy failure mode). Argmax: wave-shuffle reduce + packed u64 atomicMax
// per (block,b); next decoder cell unpacks the token (no argmax kernel).

#define BB   32
#define SEQ  128
#define HID  1024
#define NV   32000
#define TDEC 64

__device__ __forceinline__ float sgm(float x) { return 1.0f / (1.0f + expf(-x)); }
__device__ __forceinline__ float dot4(float4 a, float4 b) {
    return a.x*b.x + a.y*b.y + a.z*b.z + a.w*b.w;
}
// Unified LDS swizzle: float-offset of quad kq within a row keyed by the row.
// Bijective per 8-quad block; spreads any wave's read/write set evenly over
// the 8 bank-quads for all access patterns used below.
__device__ __forceinline__ int swz(int kq, int key) {
    return 4 * ((kq & ~7) | ((kq ^ (kq >> 3) ^ key) & 7));
}

// ---------------------------------------------------------------------------
// Fused LSTM cell. grid = 512 (2 hidden cols -> 8 gate-rows), block = 512.
// tid bits: [4:0]=ks (32-way K split, 2 quads per 256-chunk), [5]=rh (4 rows),
// [8:6]=bq (=wave id; 4 b's). Per chunk: stage A(32x256)+W(8x256) coalesced,
// then 2 quads x (4 a-reads + 4 w-reads -> 16 dot4) = 2 B/MAC.
// Gate-row r (0..7) <-> global row j0 + (r&1) + (r>>1)*HID.
// ---------------------------------------------------------------------------
template <int XK>
__global__ void __launch_bounds__(512, 4) lstm_cell(
    const float* __restrict__ xdir,   // [BB][XK] or nullptr
    const float* __restrict__ emb,    // [V][XK] or nullptr
    const int*   __restrict__ x, int xoff,               // encoder token path
    const unsigned long long* __restrict__ amaxPrev,     // decoder t>0 path
    const float* __restrict__ Wih,    // [4H][XK]
    const float* __restrict__ Whh,    // [4H][H]
    const float* __restrict__ bias,   // [4H]
    const float* __restrict__ h_in,   // [BB][H]
    float*       __restrict__ h_out,  // [BB][H]
    float*       __restrict__ c_st)   // [BB][H] in/out
{
    constexpr int NCH = (XK + HID) / 256;

    __shared__ float Ach[32 * 256];   // 32KB
    __shared__ float Wch[8 * 256];    // 8KB
    __shared__ int   tokl[32];
    float* part = Ach;                // alias: split-K partials (after compute)
    float* gs   = Wch;                // alias: reduced gates

    const int tid = threadIdx.x;
    const int ks  = tid & 31;
    const int rh  = (tid >> 5) & 1;
    const int bq  = tid >> 6;
    const int j0  = blockIdx.x * 2;

    if (emb) {
        if (tid < 32) {
            int tk;
            if (x)             tk = x[tid * SEQ + xoff];
            else if (amaxPrev) tk = (int)(~(unsigned)amaxPrev[tid]);
            else               tk = 1;  // BOS
            tokl[tid] = tk;
        }
        __syncthreads();
    }

    // staging coords (global loads coalesced; LDS stores swizzled)
    const int ar = tid >> 4, al = tid & 15;      // A: row 0..31, 4 quads each
    const int wr = tid >> 6, wl = tid & 63;      // W: row 0..7, 1 quad each
    const int wrow_g = j0 + (wr & 1) + (wr >> 1) * HID;

    const float* arowx = emb ? (emb + (size_t)tokl[ar] * XK)
                             : (xdir + (size_t)ar * XK);
    const float* arowh = h_in + (size_t)ar * HID;

    float acc[4][4];
    #pragma unroll
    for (int p = 0; p < 4; ++p)
        #pragma unroll
        for (int i = 0; i < 4; ++i) acc[p][i] = 0.0f;

    for (int ch = 0; ch < NCH; ++ch) {
        const int kb = ch * 256;   // chunk never straddles the XK boundary

        const float* as = (kb < XK) ? (arowx + kb) : (arowh + (kb - XK));
        float4 aR[4];
        #pragma unroll
        for (int i2 = 0; i2 < 4; ++i2)
            aR[i2] = *reinterpret_cast<const float4*>(as + 4 * (al + 16 * i2));
        const float* wsp = (kb < XK) ? (Wih + (size_t)wrow_g * XK + kb)
                                     : (Whh + (size_t)wrow_g * HID + (kb - XK));
        const float4 wv = *reinterpret_cast<const float4*>(wsp + wl * 4);

        __syncthreads();   // previous chunk's readers done
        #pragma unroll
        for (int i2 = 0; i2 < 4; ++i2) {
            const int kq = al + 16 * i2;
            *reinterpret_cast<float4*>(&Ach[ar * 256 + swz(kq, ar)]) = aR[i2];
        }
        *reinterpret_cast<float4*>(&Wch[wr * 256 + swz(wl, wr)]) = wv;
        __syncthreads();

        #pragma unroll
        for (int q = 0; q < 2; ++q) {
            const int kq = ks * 2 + q;
            float4 av[4], wf[4];
            #pragma unroll
            for (int i = 0; i < 4; ++i) {
                const int br = bq * 4 + i;
                av[i] = *reinterpret_cast<const float4*>(&Ach[br * 256 + swz(kq, br)]);
            }
            #pragma unroll
            for (int p = 0; p < 4; ++p) {
                const int r = rh * 4 + p;
                wf[p] = *reinterpret_cast<const float4*>(&Wch[r * 256 + swz(kq, r)]);
            }
            #pragma unroll
            for (int p = 0; p < 4; ++p)
                #pragma unroll
                for (int i = 0; i < 4; ++i)
                    acc[p][i] += dot4(av[i], wf[p]);
        }
    }

    // split-K partials (aliased onto Ach; ks-XOR'd cols: writes 2-way, reads free)
    __syncthreads();
    #pragma unroll
    for (int p = 0; p < 4; ++p)
        #pragma unroll
        for (int i = 0; i < 4; ++i)
            part[ks * 256 + (rh * 4 + p) * 32 + ((bq * 4 + i) ^ ks)] = acc[p][i];
    __syncthreads();

    if (tid < 256) {
        const int r = tid >> 5, b = tid & 31;
        float s = 0.0f;
        #pragma unroll
        for (int k2 = 0; k2 < 32; ++k2)
            s += part[k2 * 256 + r * 32 + (b ^ k2)];
        gs[r * 32 + b] = s;
    }
    __syncthreads();

    if (tid < 64) {
        const int b = tid & 31, jl = tid >> 5;
        const int j = j0 + jl;
        float g4[4];
        #pragma unroll
        for (int g = 0; g < 4; ++g)
            g4[g] = gs[(g * 2 + jl) * 32 + b] + bias[j + g * HID];
        const float cp = c_st[b * HID + j];
        const float cn = sgm(g4[1]) * cp + sgm(g4[0]) * tanhf(g4[2]);
        const float hn = sgm(g4[3]) * tanhf(cn);
        c_st[b * HID + j]  = cn;
        h_out[b * HID + j] = hn;
    }
}

// ---------------------------------------------------------------------------
// Logits + fused argmax. grid = 500 (64 v each), block = 512.
// tid bits: [1:0]=ks (4-way K split, 8 quads per 128-chunk), [5:2]=bq (2 b's),
// [8:6]=vg (8 v's). 2.5 B/MAC. Split-K partials aliased onto Wch with
// conflict-mapped layout; reduce waves own one b each (coalesced out stores,
// wave-shuffle argmax, one packed-u64 atomicMax per (block,b)).
// ---------------------------------------------------------------------------
__global__ void __launch_bounds__(512, 4) logits_kernel(
    const float* __restrict__ h1,    // [BB][H]
    const float* __restrict__ W,     // [V][H]
    const float* __restrict__ bias,  // [V]
    float*       __restrict__ out,   // [BB][TDEC][1][V]
    int t,
    unsigned long long* __restrict__ amax)   // [BB] slots for step t
{
    __shared__ float Wch[64 * 128];  // 32KB
    __shared__ float Ach[32 * 128];  // 16KB
    float* part = Wch;               // alias: 4*2048 floats after compute

    const int tid = threadIdx.x;
    const int ks  = tid & 3;
    const int bq  = (tid >> 2) & 15;
    const int vg  = tid >> 6;
    const int v0  = blockIdx.x * 64;
    const int sro = tid >> 5, scq = tid & 31;

    float acc[2][8];
    #pragma unroll
    for (int j = 0; j < 2; ++j)
        #pragma unroll
        for (int p = 0; p < 8; ++p) acc[j][p] = 0.0f;

    for (int ch = 0; ch < 8; ++ch) {
        const int k0 = ch * 128;

        float4 wR[4], aR[2];
        #pragma unroll
        for (int i = 0; i < 4; ++i)
            wR[i] = *reinterpret_cast<const float4*>(
                W + (size_t)(v0 + sro + 16 * i) * HID + k0 + scq * 4);
        #pragma unroll
        for (int i = 0; i < 2; ++i)
            aR[i] = *reinterpret_cast<const float4*>(
                h1 + (size_t)(sro + 16 * i) * HID + k0 + scq * 4);

        __syncthreads();
        #pragma unroll
        for (int i = 0; i < 4; ++i)
            *reinterpret_cast<float4*>(&Wch[(sro + 16 * i) * 128 + swz(scq, sro + 16 * i)]) = wR[i];
        #pragma unroll
        for (int i = 0; i < 2; ++i)
            *reinterpret_cast<float4*>(&Ach[(sro + 16 * i) * 128 + swz(scq, sro + 16 * i)]) = aR[i];
        __syncthreads();

        #pragma unroll
        for (int q = 0; q < 8; ++q) {
            const int kq = ks * 8 + q;
            float4 av[2], wf[8];
            #pragma unroll
            for (int j = 0; j < 2; ++j) {
                const int b = bq * 2 + j;
                av[j] = *reinterpret_cast<const float4*>(&Ach[b * 128 + swz(kq, b)]);
            }
            #pragma unroll
            for (int p = 0; p < 8; ++p) {
                const int r = vg * 8 + p;
                wf[p] = *reinterpret_cast<const float4*>(&Wch[r * 128 + swz(kq, r)]);
            }
            #pragma unroll
            for (int j = 0; j < 2; ++j)
                #pragma unroll
                for (int p = 0; p < 8; ++p)
                    acc[j][p] += dot4(av[j], wf[p]);
        }
    }

    __syncthreads();   // done reading Wch before aliased part writes
    #pragma unroll
    for (int j = 0; j < 2; ++j)
        #pragma unroll
        for (int p = 0; p < 8; ++p) {
            const int b = bq * 2 + j, vr = vg * 8 + p;
            part[ks * 2048 + b * 64 + (vr ^ b)] = acc[j][p];
        }
    __syncthreads();

    // reduce: wave 'wid' handles b = wid + 8i; lanes span the 64 vrows
    const int vrow = tid & 63;
    const int wid  = tid >> 6;
    #pragma unroll
    for (int i = 0; i < 4; ++i) {
        const int b = wid + 8 * i;
        const int c = vrow ^ b;
        const float s = part[0 * 2048 + b * 64 + c] + part[1 * 2048 + b * 64 + c]
                      + part[2 * 2048 + b * 64 + c] + part[3 * 2048 + b * 64 + c];
        const float L = s + bias[v0 + vrow];
        __builtin_nontemporal_store(L, out + ((size_t)b * TDEC + t) * (size_t)NV + v0 + vrow);

        // wave-shuffle argmax over this b's 64 vrows (first-index tie-break)
        float bv = L; int bi = v0 + vrow;
        #pragma unroll
        for (int m = 1; m < 64; m <<= 1) {
            const float ov = __shfl_xor(bv, m, 64);
            const int   oi = __shfl_xor(bi, m, 64);
            if (ov > bv || (ov == bv && oi < bi)) { bv = ov; bi = oi; }
        }
        if (vrow == 0) {
            unsigned key = __float_as_uint(bv);
            key = (key & 0x80000000u) ? ~key : (key | 0x80000000u);
            const unsigned long long pk =
                ((unsigned long long)key << 32) | (unsigned)(~bi);
            atomicMax(amax + b, pk);
        }
    }
}

__global__ void __launch_bounds__(256) init_state(
    float* h0, float* c0, float* h1, float* c1, unsigned long long* amax)
{
    const int i = blockIdx.x * 256 + threadIdx.x;
    if (i < BB * HID) { h0[i] = 0.f; c0[i] = 0.f; h1[i] = 0.f; c1[i] = 0.f; }
    if (i < TDEC * BB) amax[i] = 0ULL;
}

// ---------------------------------------------------------------------------
extern "C" void kernel_launch(void* const* d_in, const int* in_sizes, int n_in,
                              void* d_out, int out_size, void* d_ws, size_t ws_size,
                              hipStream_t stream)
{
    const int*   x       = (const int*)  d_in[0];
    const float* enc_emb = (const float*)d_in[1];
    const float* dec_emb = (const float*)d_in[2];
    const float* eWih0   = (const float*)d_in[3];
    const float* eWhh0   = (const float*)d_in[4];
    const float* eb0     = (const float*)d_in[5];
    const float* eWih1   = (const float*)d_in[6];
    const float* eWhh1   = (const float*)d_in[7];
    const float* eb1     = (const float*)d_in[8];
    const float* dWih0   = (const float*)d_in[9];
    const float* dWhh0   = (const float*)d_in[10];
    const float* db0     = (const float*)d_in[11];
    const float* dWih1   = (const float*)d_in[12];
    const float* dWhh1   = (const float*)d_in[13];
    const float* db1     = (const float*)d_in[14];
    const float* pW      = (const float*)d_in[15];
    const float* pb      = (const float*)d_in[16];
    float* out = (float*)d_out;

    // workspace layout (floats)
    float* w = (float*)d_ws;
    float* h0buf[2] = { w, w + 32768 };
    float* c0       = w + 65536;
    float* h1buf[2] = { w + 98304, w + 131072 };
    float* c1       = w + 163840;
    unsigned long long* amax = (unsigned long long*)(w + 196608);  // [TDEC][BB]

    init_state<<<dim3(128), dim3(256), 0, stream>>>(h0buf[0], c0, h1buf[0], c1, amax);

    int cur0 = 0, cur1 = 0;

    // ---- encoder: 128 steps x 2 layers ----
    for (int t = 0; t < SEQ; ++t) {
        lstm_cell<512><<<dim3(512), dim3(512), 0, stream>>>(
            nullptr, enc_emb, x, t, nullptr,
            eWih0, eWhh0, eb0, h0buf[cur0], h0buf[cur0 ^ 1], c0);
        cur0 ^= 1;
        lstm_cell<1024><<<dim3(512), dim3(512), 0, stream>>>(
            h0buf[cur0], nullptr, nullptr, 0, nullptr,
            eWih1, eWhh1, eb1, h1buf[cur1], h1buf[cur1 ^ 1], c1);
        cur1 ^= 1;
    }

    // ---- decoder: 64 greedy steps (argmax fused into logits via atomicMax) ----
    for (int t = 0; t < TDEC; ++t) {
        lstm_cell<1024><<<dim3(512), dim3(512), 0, stream>>>(
            nullptr, dec_emb, nullptr, 0, (t == 0) ? nullptr : (amax + (t - 1) * BB),
            dWih0, dWhh0, db0, h0buf[cur0], h0buf[cur0 ^ 1], c0);
        cur0 ^= 1;
        lstm_cell<1024><<<dim3(512), dim3(512), 0, stream>>>(
            h0buf[cur0], nullptr, nullptr, 0, nullptr,
            dWih1, dWhh1, db1, h1buf[cur1], h1buf[cur1 ^ 1], c1);
        cur1 ^= 1;
        logits_kernel<<<dim3(500), dim3(512), 0, stream>>>(
            h1buf[cur1], pW, pb, out, t, amax + t * BB);
    }
}